// Round 9
// baseline (936.150 us; speedup 1.0000x reference)
//
#include <hip/hip_runtime.h>
#include <hip/hip_bf16.h>

// ---------------- constants ----------------
#define Bq 32
#define Tq 16
#define Gq 512
#define NSEQ 528           // T + G
#define Cq 384
#define Hq 6
#define Sq 128
#define Kg 32              // GROUP_SIZE
#define ROWS (Bq*NSEQ)     // 16896
#define LROWS (Bq*Sq*Kg)   // 131072 local tokens

typedef unsigned short u16;
typedef short bf16x8 __attribute__((ext_vector_type(8)));   // 8 bf16 in 4 VGPRs
typedef float f32x4  __attribute__((ext_vector_type(4)));

__device__ __forceinline__ float gelu_f(float x){
    return 0.5f * x * (1.0f + erff(x * 0.70710678118654752f));
}
__device__ __forceinline__ u16 f2b(float x){
    union { float f; unsigned u; } v; v.f = x;
    return (u16)((v.u + 0x7fffu + ((v.u >> 16) & 1u)) >> 16);
}
__device__ __forceinline__ float b2f(u16 h){
    union { float f; unsigned u; } v; v.u = ((unsigned)h) << 16; return v.f;
}

// ---------------- fused concat(prompt,x) + LayerNorm(n1) ----------------
__global__ void __launch_bounds__(256) build_ln(const float* __restrict__ xin,
    const float* __restrict__ pe, const float* __restrict__ gw,
    const float* __restrict__ bw, float* __restrict__ X, u16* __restrict__ out)
{
    int w = threadIdx.x >> 6, lane = threadIdx.x & 63;
    int row = blockIdx.x*4 + w;
    if (row >= ROWS) return;
    int p = row % NSEQ; int b = row / NSEQ;
    const float* src = (p < Tq) ? (pe + (long)p*Cq)
                                : (xin + ((long)b*Gq + (p - Tq))*Cq);
    float v[6]; float s = 0.f, s2 = 0.f;
#pragma unroll
    for (int j = 0; j < 6; j++){ float x = src[lane + 64*j]; v[j] = x; s += x; s2 += x*x; }
#pragma unroll
    for (int m = 1; m < 64; m <<= 1){ s += __shfl_xor(s, m); s2 += __shfl_xor(s2, m); }
    float mean = s * (1.f/384.f);
    float var  = s2 * (1.f/384.f) - mean*mean;
    float rs   = rsqrtf(var + 1e-5f);
    float* xrow = X + (long)row*Cq;
    u16* orow = out + (long)row*Cq;
#pragma unroll
    for (int j = 0; j < 6; j++){
        int c = lane + 64*j;
        xrow[c] = v[j];
        orow[c] = f2b((v[j] - mean) * rs * gw[c] + bw[c]);
    }
}

// ---------------- weight conversion fp32 -> bf16 (6 matrices) ----------------
__global__ void __launch_bounds__(256) conv6(const float* __restrict__ s0,
    const float* __restrict__ s1, const float* __restrict__ s2,
    const float* __restrict__ s3, const float* __restrict__ s4,
    const float* __restrict__ s5, u16* __restrict__ dst)
{
    long i = (long)blockIdx.x*256 + threadIdx.x;
    if (i >= 2359296) return;
    float v;
    if      (i <  442368) v = s0[i];
    else if (i <  589824) v = s1[i -  442368];
    else if (i < 1179648) v = s2[i -  589824];
    else if (i < 1769472) v = s3[i - 1179648];
    else if (i < 2211840) v = s4[i - 1769472];
    else                  v = s5[i - 2211840];
    dst[i] = f2b(v);
}

// ---------------- mask fp32 -> bf16 additive bias ----------------
__global__ void __launch_bounds__(256) conv_mask(const float* __restrict__ m,
    u16* __restrict__ bias16)
{
    long i = (long)blockIdx.x*256 + threadIdx.x;
    if (i >= (long)Bq*Gq*Gq) return;
    bias16[i] = f2b(-100000.0f * m[i]);
}

// ---------------- LayerNorm, one wave per row, bf16 out ----------------
__global__ void __launch_bounds__(256) ln_rows(const float* __restrict__ in,
    const float* __restrict__ gw, const float* __restrict__ bw,
    u16* __restrict__ out, int rows)
{
    int w = threadIdx.x >> 6, lane = threadIdx.x & 63;
    int row = blockIdx.x*4 + w;
    if (row >= rows) return;
    const float* xr = in + (long)row*Cq;
    float v[6]; float s = 0.f, s2 = 0.f;
#pragma unroll
    for (int j = 0; j < 6; j++){ float x = xr[lane + 64*j]; v[j] = x; s += x; s2 += x*x; }
#pragma unroll
    for (int m = 1; m < 64; m <<= 1){ s += __shfl_xor(s, m); s2 += __shfl_xor(s2, m); }
    float mean = s * (1.f/384.f);
    float var  = s2 * (1.f/384.f) - mean*mean;
    float rs   = rsqrtf(var + 1e-5f);
    u16* orow = out + (long)row*Cq;
#pragma unroll
    for (int j = 0; j < 6; j++){
        int c = lane + 64*j;
        orow[c] = f2b((v[j] - mean) * rs * gw[c] + bw[c]);
    }
}

// ---------------- bf16 MFMA GEMM: C = epi(A @ W^T) ----------------
// epi: 0 none->f32, 1 +bias->f32, 2 gelu(+bias)->bf16, 3 Cf += acc+bias (f32 RMW),
//      4 (+bias if given)->bf16
__global__ void __launch_bounds__(256) gemm_bf16(const u16* __restrict__ A,
    const u16* __restrict__ W, const float* __restrict__ bias,
    float* __restrict__ Cf, u16* __restrict__ Cb, int M, int N, int K, int epi)
{
    __shared__ u16 As[128*40];
    __shared__ u16 Ws[128*40];
    int t = threadIdx.x;
    int m0 = blockIdx.y*128, n0 = blockIdx.x*128;
    int wv = t >> 6, lane = t & 63;
    int wm = (wv >> 1)*64, wn = (wv & 1)*64;
    int fm = lane & 15;
    int fk = (lane >> 4) * 8;
    int sr = t >> 2;
    int sc8 = (t & 3) * 8;
    f32x4 acc[4][4];
#pragma unroll
    for (int i = 0; i < 4; i++)
#pragma unroll
        for (int j = 0; j < 4; j++) acc[i][j] = (f32x4){0.f,0.f,0.f,0.f};

    for (int k0 = 0; k0 < K; k0 += 32){
        *(uint4*)&As[sr*40 + sc8]      = *(const uint4*)(A + (long)(m0+sr)*K    + k0 + sc8);
        *(uint4*)&As[(sr+64)*40 + sc8] = *(const uint4*)(A + (long)(m0+sr+64)*K + k0 + sc8);
        *(uint4*)&Ws[sr*40 + sc8]      = *(const uint4*)(W + (long)(n0+sr)*K    + k0 + sc8);
        *(uint4*)&Ws[(sr+64)*40 + sc8] = *(const uint4*)(W + (long)(n0+sr+64)*K + k0 + sc8);
        __syncthreads();
        bf16x8 af[4], bf[4];
#pragma unroll
        for (int im = 0; im < 4; im++) af[im] = *(const bf16x8*)&As[(wm + im*16 + fm)*40 + fk];
#pragma unroll
        for (int in = 0; in < 4; in++) bf[in] = *(const bf16x8*)&Ws[(wn + in*16 + fm)*40 + fk];
#pragma unroll
        for (int im = 0; im < 4; im++)
#pragma unroll
            for (int in = 0; in < 4; in++)
                acc[im][in] = __builtin_amdgcn_mfma_f32_16x16x32_bf16(af[im], bf[in], acc[im][in], 0, 0, 0);
        __syncthreads();
    }
    int lr = lane >> 4, lc = lane & 15;
#pragma unroll
    for (int im = 0; im < 4; im++){
#pragma unroll
        for (int in = 0; in < 4; in++){
#pragma unroll
            for (int r = 0; r < 4; r++){
                int m = m0 + wm + im*16 + lr*4 + r;
                int n = n0 + wn + in*16 + lc;
                float v = acc[im][in][r];
                if (epi >= 1 && bias) v += bias[n];
                if (epi == 2) v = gelu_f(v);
                long off = (long)m*N + n;
                if (epi == 3) v += Cf[off];
                if (epi == 2 || epi == 4) Cb[off] = f2b(v);
                else                      Cf[off] = v;
            }
        }
    }
}

// ---------------- flash-style MFMA global attention v3 ----------------
__global__ void __launch_bounds__(256) attn_mfma(const u16* __restrict__ QKVg,
    const u16* __restrict__ bias16, u16* __restrict__ out)
{
    __shared__ u16 Ks[32*72];
    __shared__ u16 Vt[64*40];
    __shared__ u16 Bs[64*36];
    __shared__ u16 Pb[4][16*40];
    int blk = blockIdx.x;
    int xcd = blk & 7; int r0 = blk >> 3;
    int bb = r0 & 3;  int rr = r0 >> 2;
    int h = rr % 6;   int qt = rr / 6;
    int b = xcd + 8*bb;
    int t = threadIdx.x; int w = t >> 6; int lane = t & 63;
    int fr  = lane & 15;
    int fko = (lane >> 4) * 8;
    int colj = lane & 15;
    int rgrp = (lane >> 4) * 4;
    int qb0 = qt*64;
    int q0 = qb0 + w*16;

    int qr = q0 + fr; int qrc = qr < NSEQ ? qr : NSEQ-1;
    const u16* qbase = QKVg + (long)(b*NSEQ + qrc)*1152 + h*64;
    bf16x8 aq0 = *(const bf16x8*)(qbase + fko);
    bf16x8 aq1 = *(const bf16x8*)(qbase + 32 + fko);

    f32x4 oacc[4];
#pragma unroll
    for (int d = 0; d < 4; d++) oacc[d] = (f32x4){0.f,0.f,0.f,0.f};
    float lsum[4] = {0.f, 0.f, 0.f, 0.f};

    int skey = t >> 3;
    int sd8  = (t & 7) * 8;
    int brow = t >> 2;
    int bc8  = (t & 3) * 8;

    for (int kc = 0; kc < 17; kc++){
        __syncthreads();
        {
            int j = kc*32 + skey;
            bf16x8 kv = {0,0,0,0,0,0,0,0};
            bf16x8 vv = {0,0,0,0,0,0,0,0};
            if (j < NSEQ){
                const u16* kb = QKVg + (long)(b*NSEQ + j)*1152 + 384 + h*64 + sd8;
                kv = *(const bf16x8*)kb;
                vv = *(const bf16x8*)(kb + 384);
            }
            *(bf16x8*)&Ks[skey*72 + sd8] = kv;
#pragma unroll
            for (int e = 0; e < 8; e++) Vt[(sd8+e)*40 + skey] = (u16)vv[e];
        }
        {
            int qi = qb0 + brow;
            int jj = kc*32 + bc8;
            uint4 bz = make_uint4(0u,0u,0u,0u);
            if (qi < Gq && jj < Gq)
                bz = *(const uint4*)(bias16 + ((long)b*Gq + qi)*Gq + jj);
            *(uint4*)&Bs[brow*36 + bc8] = bz;
        }
        __syncthreads();
        f32x4 s[2];
#pragma unroll
        for (int sub = 0; sub < 2; sub++){
            bf16x8 bk0 = *(const bf16x8*)&Ks[(sub*16 + fr)*72 + fko];
            bf16x8 bk1 = *(const bf16x8*)&Ks[(sub*16 + fr)*72 + 32 + fko];
            f32x4 z = (f32x4){0.f,0.f,0.f,0.f};
            z = __builtin_amdgcn_mfma_f32_16x16x32_bf16(aq0, bk0, z, 0, 0, 0);
            z = __builtin_amdgcn_mfma_f32_16x16x32_bf16(aq1, bk1, z, 0, 0, 0);
            s[sub] = z;
        }
#pragma unroll
        for (int sub = 0; sub < 2; sub++){
#pragma unroll
            for (int r = 0; r < 4; r++){
                int jj = kc*32 + sub*16 + colj;
                float sv = s[sub][r] * 0.125f
                         + b2f(Bs[(w*16 + rgrp + r)*36 + sub*16 + colj]);
                if (jj >= NSEQ) sv = -1e30f;
                float e = __expf(sv);
                lsum[r] += e;
                Pb[w][(rgrp + r)*40 + sub*16 + colj] = f2b(e);
            }
        }
        __syncthreads();
        bf16x8 ap = *(const bf16x8*)&Pb[w][fr*40 + fko];
#pragma unroll
        for (int d = 0; d < 4; d++){
            bf16x8 bv = *(const bf16x8*)&Vt[(d*16 + fr)*40 + fko];
            oacc[d] = __builtin_amdgcn_mfma_f32_16x16x32_bf16(ap, bv, oacc[d], 0, 0, 0);
        }
    }
#pragma unroll
    for (int r = 0; r < 4; r++){
#pragma unroll
        for (int mm = 1; mm < 16; mm <<= 1) lsum[r] += __shfl_xor(lsum[r], mm);
    }
#pragma unroll
    for (int r = 0; r < 4; r++){
        int qi = q0 + rgrp + r;
        if (qi < NSEQ){
            float inv = 1.0f / lsum[r];
#pragma unroll
            for (int d = 0; d < 4; d++)
                out[((long)(b*NSEQ + qi))*Cq + h*64 + d*16 + colj] = f2b(oacc[d][r]*inv);
        }
    }
}

// ---------------- fused adapter (one wave per row) ----------------
__global__ void __launch_bounds__(256) adapter_fused(const float* __restrict__ xfn,
    const float* __restrict__ resid,
    const float* __restrict__ dw, const float* __restrict__ db,
    const float* __restrict__ uw, const float* __restrict__ ub,
    const float* __restrict__ gatep,
    const float* __restrict__ lng, const float* __restrict__ lnb,
    float* __restrict__ Xout, u16* __restrict__ x16out,
    u16* __restrict__ ln16, int rows)
{
    int w = threadIdx.x >> 6, lane = threadIdx.x & 63;
    int row = blockIdx.x*4 + w;
    if (row >= rows) return;
    const float* xr = xfn + (long)row*Cq;
    float xv[6];
#pragma unroll
    for (int j = 0; j < 6; j++) xv[j] = xr[lane + 64*j];
    float hid[16];
#pragma unroll
    for (int r = 0; r < 16; r++){
        const float* dr = dw + r*Cq;
        float p = 0.f;
#pragma unroll
        for (int j = 0; j < 6; j++) p += xv[j]*dr[lane + 64*j];
#pragma unroll
        for (int mm = 1; mm < 64; mm <<= 1) p += __shfl_xor(p, mm);
        hid[r] = gelu_f(p + db[r]);
    }
    float gate = gatep ? gatep[0] : 1.0f;
    float ov[6];
    float s = 0.f, s2 = 0.f;
#pragma unroll
    for (int j = 0; j < 6; j++){
        int c = lane + 64*j;
        const float* uc = uw + c*16;
        float a = 0.f;
#pragma unroll
        for (int r = 0; r < 16; r++) a += hid[r]*uc[r];
        float v = gate * (a + ub[c] + xv[j]);
        if (resid) v += resid[(long)row*Cq + c];
        ov[j] = v;
        Xout[(long)row*Cq + c] = v;
        if (x16out) x16out[(long)row*Cq + c] = f2b(v);
        s += v; s2 += v*v;
    }
    if (lng){
#pragma unroll
        for (int m = 1; m < 64; m <<= 1){ s += __shfl_xor(s, m); s2 += __shfl_xor(s2, m); }
        float mean = s * (1.f/384.f);
        float var  = s2 * (1.f/384.f) - mean*mean;
        float rs   = rsqrtf(var + 1e-5f);
        u16* orow = ln16 + (long)row*Cq;
#pragma unroll
        for (int j = 0; j < 6; j++){
            int c = lane + 64*j;
            orow[c] = f2b((ov[j] - mean)*rs*lng[c] + lnb[c]);
        }
    }
}

// ---------------- fused local branch: attn + proj + pool, 1 group/block -----
// QKVg: (16896,1152) bf16. W: a1_proj (384x384) bf16. Output: vis (4096,384) f32.
// Attention P*V result stays in LDS (Ao, gemm-style 32-k-chunk layout), proj
// runs in-block with W streamed from L2, pool epilogue as in gemm_pool.
__global__ void __launch_bounds__(256) local_fused(const u16* __restrict__ QKVg,
    const int* __restrict__ idx, const int* __restrict__ cidx,
    const u16* __restrict__ W, const float* __restrict__ bias,
    const u16* __restrict__ X16, const float* __restrict__ bng,
    const float* __restrict__ bnb, float* __restrict__ vis)
{
    __shared__ u16 Qs[32*72];
    __shared__ u16 Ksm[32*72];
    __shared__ u16 Vt[64*40];
    __shared__ float sc[32*36];
    __shared__ u16 Pa[32*40];
    __shared__ float linv[32];
    __shared__ u16 Ao[12*32*40];   // proj A operand: [k-chunk][32 rows][32+8 pad]
    __shared__ int rows[32];
    int g = blockIdx.x;
    int t = threadIdx.x;
    int w = t >> 6, lane = t & 63;
    if (t < 32) rows[t] = idx[g*Kg + t];
    __syncthreads();
    int srow = t & 31;
    int d8   = (t >> 5) * 8;
    int fr = lane & 15, fko = (lane >> 4)*8;
    int colj = lane & 15, rgrp = (lane >> 4)*4;
    int it = w >> 1, jt = w & 1;
    int smrow = w*8 + (lane >> 3);
    int smc   = (lane & 7) * 4;

    for (int h = 0; h < Hq; h++){
        {
            const u16* base = QKVg + (long)rows[srow]*1152 + h*64 + d8;
            bf16x8 qv = *(const bf16x8*)(base);
            bf16x8 kv = *(const bf16x8*)(base + 384);
            bf16x8 vv = *(const bf16x8*)(base + 768);
            *(bf16x8*)&Qs[srow*72 + d8]  = qv;
            *(bf16x8*)&Ksm[srow*72 + d8] = kv;
#pragma unroll
            for (int e = 0; e < 8; e++) Vt[(d8+e)*40 + srow] = (u16)vv[e];
        }
        __syncthreads();
        {
            bf16x8 a0 = *(const bf16x8*)&Qs[(it*16+fr)*72 + fko];
            bf16x8 a1 = *(const bf16x8*)&Qs[(it*16+fr)*72 + 32 + fko];
            bf16x8 b0 = *(const bf16x8*)&Ksm[(jt*16+fr)*72 + fko];
            bf16x8 b1 = *(const bf16x8*)&Ksm[(jt*16+fr)*72 + 32 + fko];
            f32x4 z = (f32x4){0.f,0.f,0.f,0.f};
            z = __builtin_amdgcn_mfma_f32_16x16x32_bf16(a0, b0, z, 0, 0, 0);
            z = __builtin_amdgcn_mfma_f32_16x16x32_bf16(a1, b1, z, 0, 0, 0);
#pragma unroll
            for (int r = 0; r < 4; r++)
                sc[(it*16 + rgrp + r)*36 + jt*16 + colj] = z[r]*0.125f;
        }
        __syncthreads();
        {
            float4 s4 = *(const float4*)&sc[smrow*36 + smc];
            float mx = fmaxf(fmaxf(s4.x, s4.y), fmaxf(s4.z, s4.w));
#pragma unroll
            for (int mm = 1; mm < 8; mm <<= 1) mx = fmaxf(mx, __shfl_xor(mx, mm));
            float p0 = __expf(s4.x - mx), p1 = __expf(s4.y - mx);
            float p2 = __expf(s4.z - mx), p3 = __expf(s4.w - mx);
            float sm = p0 + p1 + p2 + p3;
#pragma unroll
            for (int mm = 1; mm < 8; mm <<= 1) sm += __shfl_xor(sm, mm);
            if ((lane & 7) == 0) linv[smrow] = 1.0f / sm;
            Pa[smrow*40 + smc + 0] = f2b(p0);
            Pa[smrow*40 + smc + 1] = f2b(p1);
            Pa[smrow*40 + smc + 2] = f2b(p2);
            Pa[smrow*40 + smc + 3] = f2b(p3);
        }
        __syncthreads();
        {
            bf16x8 ap = *(const bf16x8*)&Pa[(it*16+fr)*40 + fko];
#pragma unroll
            for (int dd = 0; dd < 2; dd++){
                int dt = jt + dd*2;
                bf16x8 bv = *(const bf16x8*)&Vt[(dt*16+fr)*40 + fko];
                f32x4 o = (f32x4){0.f,0.f,0.f,0.f};
                o = __builtin_amdgcn_mfma_f32_16x16x32_bf16(ap, bv, o, 0, 0, 0);
#pragma unroll
                for (int r = 0; r < 4; r++){
                    int row = it*16 + rgrp + r;
                    int c = h*64 + dt*16 + colj;
                    Ao[((c >> 5)*32 + row)*40 + (c & 31)] = f2b(o[r] * linv[row]);
                }
            }
        }
        __syncthreads();
    }
    // ---- proj + pool: wave w handles col-tiles w*6 .. w*6+5 ----
    int crow = cidx[g];
#pragma unroll
    for (int ct = 0; ct < 6; ct++){
        int n0 = (w*6 + ct)*16;
        f32x4 acc0 = (f32x4){0.f,0.f,0.f,0.f};
        f32x4 acc1 = (f32x4){0.f,0.f,0.f,0.f};
        const u16* wbase = W + (long)(n0 + fr)*Cq + fko;
#pragma unroll
        for (int kc = 0; kc < 12; kc++){
            bf16x8 bfr = *(const bf16x8*)(wbase + kc*32);
            bf16x8 a0  = *(const bf16x8*)&Ao[(kc*32 + fr)*40 + fko];
            bf16x8 a1  = *(const bf16x8*)&Ao[(kc*32 + 16 + fr)*40 + fko];
            acc0 = __builtin_amdgcn_mfma_f32_16x16x32_bf16(a0, bfr, acc0, 0, 0, 0);
            acc1 = __builtin_amdgcn_mfma_f32_16x16x32_bf16(a1, bfr, acc1, 0, 0, 0);
        }
        int c = n0 + colj;
        float pb = bias[c];
        float vmax = -3e38f, vsum = 0.f;
#pragma unroll
        for (int r = 0; r < 4; r++){
            int r0 = rgrp + r;
            float v0 = acc0[r] + pb + b2f(X16[(long)rows[r0]*Cq + c]);
            float v1 = acc1[r] + pb + b2f(X16[(long)rows[r0 + 16]*Cq + c]);
            vmax = fmaxf(vmax, fmaxf(v0, v1)); vsum += v0 + v1;
        }
        vmax = fmaxf(vmax, __shfl_xor(vmax, 16)); vsum += __shfl_xor(vsum, 16);
        vmax = fmaxf(vmax, __shfl_xor(vmax, 32)); vsum += __shfl_xor(vsum, 32);
        if (lane < 16){
            float lcv = vmax + vsum*(1.f/32.f);
            float u = gelu_f(lcv*bng[c]*0.9999950000374997f + bnb[c]);
            vis[(long)g*Cq + c] = u + 0.4f*b2f(X16[(long)crow*Cq + c]);
        }
    }
}

// ---------------- inverse-distance interp: 8 points/block share vis reads ----
__global__ void __launch_bounds__(128) interp_k(const float* __restrict__ Xf,
    const float* __restrict__ vis, const float* __restrict__ c1,
    const float* __restrict__ c2, float* __restrict__ newx)
{
    __shared__ float wsh[8*128];
    __shared__ float inv8[8];
    int blk = blockIdx.x;
    int b = blk >> 6, nt = blk & 63;
    int tid = threadIdx.x;
#pragma unroll
    for (int i = 0; i < 8; i++){
        int id = tid + i*128;
        int nl = id >> 7, s = id & 127;
        const float* p1 = c1 + ((long)b*Gq + nt*8 + nl)*3;
        const float* p2 = c2 + ((long)b*Sq + s)*3;
        float x1 = p1[0], y1 = p1[1], z1 = p1[2];
        float x2 = p2[0], y2 = p2[1], z2 = p2[2];
        float d = (x1*x1 + y1*y1 + z1*z1) + (x2*x2 + y2*y2 + z2*z2)
                - 2.f*(x1*x2 + y1*y2 + z1*z2);
        wsh[nl*128 + s] = 1.f/(d + 1e-8f);
    }
    __syncthreads();
    if (tid < 8){
        float sum = 0.f;
        for (int s = 0; s < Sq; s++) sum += wsh[tid*128 + s];
        inv8[tid] = 1.f/sum;
    }
    __syncthreads();
    float acc[8][3];
#pragma unroll
    for (int n = 0; n < 8; n++){ acc[n][0] = 0.f; acc[n][1] = 0.f; acc[n][2] = 0.f; }
    const float* vb = vis + (long)b*Sq*Cq + tid;
    for (int s = 0; s < Sq; s++){
        float v0 = vb[s*Cq], v1 = vb[s*Cq + 128], v2 = vb[s*Cq + 256];
#pragma unroll
        for (int n = 0; n < 8; n++){
            float wq = wsh[n*128 + s];
            acc[n][0] += wq*v0; acc[n][1] += wq*v1; acc[n][2] += wq*v2;
        }
    }
#pragma unroll
    for (int n = 0; n < 8; n++){
        int gn = nt*8 + n;
        const float* xr = Xf + ((long)(b*NSEQ + Tq + gn))*Cq;
        float* orow = newx + ((long)(b*Gq + gn))*Cq;
        float sf = 0.4f * inv8[n];
        orow[tid]       = xr[tid]       + sf*acc[n][0];
        orow[tid + 128] = xr[tid + 128] + sf*acc[n][1];
        orow[tid + 256] = xr[tid + 256] + sf*acc[n][2];
    }
}

// ---------------- launch ----------------
extern "C" void kernel_launch(void* const* d_in, const int* in_sizes, int n_in,
                              void* d_out, int out_size, void* d_ws, size_t ws_size,
                              hipStream_t stream)
{
    const float* x_in  = (const float*)d_in[0];
    const float* mask  = (const float*)d_in[1];
    const float* c1p   = (const float*)d_in[2];
    const float* c2p   = (const float*)d_in[3];
    const float* pe    = (const float*)d_in[5];
    const float* n1g   = (const float*)d_in[6];
    const float* n1b   = (const float*)d_in[7];
    const float* qkvw  = (const float*)d_in[8];
    const float* projw = (const float*)d_in[9];
    const float* projb = (const float*)d_in[10];
    const float* n2g   = (const float*)d_in[11];
    const float* n2b   = (const float*)d_in[12];
    const float* fc1w  = (const float*)d_in[13];
    const float* fc1b  = (const float*)d_in[14];
    const float* fc2w  = (const float*)d_in[15];
    const float* fc2b  = (const float*)d_in[16];
    const float* gate  = (const float*)d_in[17];
    const float* addw  = (const float*)d_in[18];
    const float* addb  = (const float*)d_in[19];
    const float* aduw  = (const float*)d_in[20];
    const float* adub  = (const float*)d_in[21];
    const float* ad1dw = (const float*)d_in[22];
    const float* ad1db = (const float*)d_in[23];
    const float* ad1uw = (const float*)d_in[24];
    const float* ad1ub = (const float*)d_in[25];
    const float* bng   = (const float*)d_in[26];
    const float* bnb   = (const float*)d_in[27];
    const float* a1qkvw= (const float*)d_in[28];
    const float* a1pw  = (const float*)d_in[29];
    const float* a1pb  = (const float*)d_in[30];
    const float* n3g   = (const float*)d_in[31];
    const float* n3b   = (const float*)d_in[32];
    const int*   idxp  = (const int*)d_in[33];
    const int*   cidxp = (const int*)d_in[34];

    // ---- workspace layout (bytes), total 252.4 MB ----
    char* w = (char*)d_ws;
    float* X    = (float*)w;                       // 16896x384 f32   [0, 25952256)
    u16*   WB   = (u16*)(w + 25952256);            // bf16 weights
    u16*   Bb16 = (u16*)(w + 30670848);            // 16896x384 bf16
    char*  R1   = w + 43646976;                    // 100663296 B (bias16 / hid16)
    char*  R2   = R1 + 100663296;                  // 100663296 B (QKVg/C1/newx + X16)
    float* V    = (float*)(R2 + 100663296);        // 4096x384 f32

    u16* qkvw16  = WB;
    u16* projw16 = WB +  442368;
    u16* fc1w16  = WB +  589824;
    u16* fc2w16  = WB + 1179648;
    u16* a1qkv16 = WB + 1769472;
    u16* a1pw16  = WB + 2211840;

    u16*   bias16 = (u16*)R1;       // 32x512x512 bf16 (dead before fc1)
    u16*   hid16  = (u16*)R1;       // 16896x1536 bf16 (MLP phase)
    u16*   QKVg   = (u16*)R2;       // 16896x1152 bf16 [R2, R2+38.9MB)
    float* C1     = (float*)R2;     // 16896x384 f32 x_fn (dead after adapter#1)
    float* newx   = (float*)R2;     // 16384x384 f32 (interp out; QKVg dead then)
    u16*   X16    = (u16*)(R2 + 41943040);  // 16896x384 bf16 [40MB, 53MB) of R2

    conv6<<<9216, 256, 0, stream>>>(qkvw, projw, fc1w, fc2w, a1qkvw, a1pw, WB);
    conv_mask<<<32768, 256, 0, stream>>>(mask, bias16);
    build_ln<<<4224, 256, 0, stream>>>(x_in, pe, n1g, n1b, X, Bb16);
    gemm_bf16<<<dim3(9, 132), 256, 0, stream>>>(Bb16, qkvw16, nullptr, nullptr, QKVg,
                                                ROWS, 1152, Cq, 4);
    attn_mfma<<<1728, 256, 0, stream>>>(QKVg, bias16, Bb16);
    gemm_bf16<<<dim3(3, 132), 256, 0, stream>>>(Bb16, projw16, projb, X, nullptr,
                                                ROWS, Cq, Cq, 3);
    ln_rows<<<4224, 256, 0, stream>>>(X, n2g, n2b, Bb16, ROWS);
    gemm_bf16<<<dim3(12, 132), 256, 0, stream>>>(Bb16, fc1w16, fc1b, nullptr, hid16,
                                                 ROWS, 1536, Cq, 2);
    gemm_bf16<<<dim3(3, 132), 256, 0, stream>>>(hid16, fc2w16, fc2b, C1, nullptr,
                                                ROWS, Cq, 1536, 1);
    // fused: x = gate*adapter(x_fn)+x ; X16 = bf16(x); Bb16 = LN3(x)
    adapter_fused<<<4224, 256, 0, stream>>>(C1, X, addw, addb, aduw, adub, gate,
                                            n3g, n3b, X, X16, Bb16, ROWS);
    // local branch (fused attn+proj+pool)
    gemm_bf16<<<dim3(9, 132), 256, 0, stream>>>(Bb16, a1qkv16, nullptr, nullptr, QKVg,
                                                ROWS, 1152, Cq, 4);
    local_fused<<<4096, 256, 0, stream>>>(QKVg, idxp, cidxp, a1pw16, a1pb,
                                          X16, bng, bnb, V);
    interp_k<<<2048, 128, 0, stream>>>(X, V, c1p, c2p, newx);
    // fused final adapter -> d_out
    adapter_fused<<<4096, 256, 0, stream>>>(newx, nullptr, ad1dw, ad1db, ad1uw, ad1ub,
                                            nullptr, nullptr, nullptr,
                                            (float*)d_out, nullptr, nullptr, Bq*Gq);
}